// Round 1
// baseline (14778.040 us; speedup 1.0000x reference)
//
#include <hip/hip_runtime.h>

typedef unsigned short u16;
typedef unsigned int u32;
typedef short bf16x8 __attribute__((ext_vector_type(8)));
typedef float f32x4 __attribute__((ext_vector_type(4)));

#define B_ 16
#define T_ 128
#define H_ 512
#define V_ 32000
#define G3 1536
#define STEPS 127

// ---------------- ws layout (float units) ----------------
#define OFF_VT    0u            // [2048][512]  m=b*128+t
#define OFF_P     1048576u      // [2048][1536] m=b*128+t
#define OFF_GIX   4194304u      // [2048][1536] m=s*16+b
#define OFF_HALL  7340032u      // [2048][512]  m=s*16+b
#define OFF_Q     8388608u      // [16][512]
#define OFF_GH    8396800u      // [16][1536]
#define OFF_SC    8421376u      // [16][128]
#define OFF_BAR   8423424u      // 8192 u32 (256 blocks * 32 stride)
#define OFF_AENC  8431616u      // bf16 [2048][512]
#define OFF_AEMB  8955904u
#define OFF_AH    9480192u
#define OFF_BWV   10004480u     // bf16 [512][512]
#define OFF_BWIH1 10135552u     // bf16 [1536][512]
#define OFF_BWIH2 10528768u
#define OFF_BWO   10921984u     // bf16 [32000][512]

__device__ __forceinline__ u16 f2bf(float f) {
  union { float f; u32 u; } x; x.f = f;
  u32 r = x.u + 0x7fffu + ((x.u >> 16) & 1u);
  return (u16)(r >> 16);
}
__device__ __forceinline__ float bf2f(u16 u) {
  union { u32 u; float f; } x; x.u = ((u32)u) << 16;
  return x.f;
}
__device__ __forceinline__ float wred(float v) {
#pragma unroll
  for (int off = 32; off > 0; off >>= 1) v += __shfl_down(v, off, 64);
  return v; // valid in lane 0
}

// ---------------- small utility kernels ----------------
__global__ void k_init(float* __restrict__ out, u32* __restrict__ bars) {
  int idx = blockIdx.x * 256 + threadIdx.x;
  if (idx < 512000) {            // out[:,0,:] = 0
    int b = idx / 32000; int v = idx - b * 32000;
    out[(size_t)b * 4096000 + v] = 0.f;
  }
  if (idx < 8192) bars[idx] = 0u;
}

__global__ void k_f2bf(const float* __restrict__ src, u16* __restrict__ dst, int n) {
  int idx = blockIdx.x * 256 + threadIdx.x;
  if (idx < n) dst[idx] = f2bf(src[idx]);
}

// take 512-wide column slice [off, off+512) of rows with leading dim ld
__global__ void k_f2bf_sub(const float* __restrict__ src, u16* __restrict__ dst,
                           int n, int ld, int off) {
  int idx = blockIdx.x * 256 + threadIdx.x;
  if (idx < n) {
    int r = idx >> 9, c = idx & 511;
    dst[idx] = f2bf(src[(size_t)r * ld + off + c]);
  }
}

// A_emb[m= s*16+b][c] = bf16(emb[tok(b,s)][c]), tok = s==0 ? BOS(1) : target[b][s]
__global__ void k_gather(const float* __restrict__ emb, const int* __restrict__ tgt,
                         u16* __restrict__ dst, int n) {
  int idx = blockIdx.x * 256 + threadIdx.x;
  if (idx < n) {
    int m = idx >> 9, c = idx & 511;
    int b = m & 15, s = m >> 4;
    int tok = (s == 0) ? 1 : tgt[b * 128 + s];
    dst[idx] = f2bf(emb[(size_t)tok * 512 + c]);
  }
}

// ---------------- bf16 MFMA GEMM: C[m][n] = sum_k A[m][k]*B[n][k] + bias[n] ----------------
// A: [gridDim.y*128][512] bf16, B: [N][512] bf16. mode 0: C[m*ldc+n]. mode 1: decoder remap.
__global__ __launch_bounds__(256) void gemm_bf16(
    const u16* __restrict__ A, const u16* __restrict__ Bm,
    const float* __restrict__ bias, float* __restrict__ C,
    int ldc, int mode) {
  __shared__ u16 As[128 * 32];
  __shared__ u16 Bs[128 * 32];
  const int tid = threadIdx.x;
  const int lane = tid & 63;
  const int wave = tid >> 6;
  const int lr = lane & 15;
  const int quad = lane >> 4;
  const int wm = (wave >> 1) * 64;
  const int wn = (wave & 1) * 64;
  const int bm = blockIdx.y * 128;
  const int bn = blockIdx.x * 128;
  const int srow = tid >> 1;          // 0..127
  const int shalf = (tid & 1) * 16;   // 0 or 16

  f32x4 acc[4][4];
#pragma unroll
  for (int i = 0; i < 4; ++i)
#pragma unroll
    for (int j = 0; j < 4; ++j) acc[i][j] = (f32x4){0.f, 0.f, 0.f, 0.f};

  for (int kt = 0; kt < 16; ++kt) {
    const u16* gA = A + (size_t)(bm + srow) * 512 + kt * 32 + shalf;
    const u16* gB = Bm + (size_t)(bn + srow) * 512 + kt * 32 + shalf;
    uint4 a0 = *(const uint4*)gA;
    uint4 a1 = *(const uint4*)(gA + 8);
    uint4 b0 = *(const uint4*)gB;
    uint4 b1 = *(const uint4*)(gB + 8);
    __syncthreads();
    *(uint4*)&As[srow * 32 + shalf] = a0;
    *(uint4*)&As[srow * 32 + shalf + 8] = a1;
    *(uint4*)&Bs[srow * 32 + shalf] = b0;
    *(uint4*)&Bs[srow * 32 + shalf + 8] = b1;
    __syncthreads();
    bf16x8 af[4], bf[4];
#pragma unroll
    for (int i = 0; i < 4; ++i)
      af[i] = *(const bf16x8*)&As[(wm + i * 16 + lr) * 32 + quad * 8];
#pragma unroll
    for (int j = 0; j < 4; ++j)
      bf[j] = *(const bf16x8*)&Bs[(wn + j * 16 + lr) * 32 + quad * 8];
#pragma unroll
    for (int i = 0; i < 4; ++i)
#pragma unroll
      for (int j = 0; j < 4; ++j)
        acc[i][j] = __builtin_amdgcn_mfma_f32_16x16x32_bf16(af[i], bf[j], acc[i][j], 0, 0, 0);
  }

#pragma unroll
  for (int j = 0; j < 4; ++j) {
    int ng = bn + wn + j * 16 + lr;
    float bv = bias ? bias[ng] : 0.f;
#pragma unroll
    for (int i = 0; i < 4; ++i) {
      int mg0 = bm + wm + i * 16 + quad * 4;
#pragma unroll
      for (int r = 0; r < 4; ++r) {
        int mg = mg0 + r;
        float v = acc[i][j][r] + bv;
        if (mode == 0) {
          C[(size_t)mg * ldc + ng] = v;
        } else {
          if (mg < 2032) {
            int s = mg >> 4, b = mg & 15;
            C[(size_t)((b << 7) + s + 1) * 32000 + ng] = v;
          }
        }
      }
    }
  }
}

// ---------------- sequential recurrence (persistent, manual grid barrier) ----------------
__device__ __forceinline__ void gbar(u32* bars, u32 phase) {
  __threadfence();
  __syncthreads();
  if (threadIdx.x == 0)
    __hip_atomic_store(&bars[blockIdx.x * 32], phase, __ATOMIC_RELEASE, __HIP_MEMORY_SCOPE_AGENT);
  u32 v;
  for (;;) {
    v = __hip_atomic_load(&bars[threadIdx.x * 32], __ATOMIC_ACQUIRE, __HIP_MEMORY_SCOPE_AGENT);
    if (v >= phase) break;
    __builtin_amdgcn_s_sleep(2);
  }
  __syncthreads();
}

__global__ __launch_bounds__(256, 1) void seq_kernel(
    const float* __restrict__ Wq, const float* __restrict__ bq,
    const float* __restrict__ Wc, const float* __restrict__ bc,
    const float* __restrict__ Whh, const float* __restrict__ bhh,
    const float* __restrict__ h0, const int* __restrict__ mask,
    float* __restrict__ ws_vt, float* __restrict__ ws_P,
    float* __restrict__ ws_gix, float* __restrict__ ws_hall,
    float* __restrict__ ws_q, float* __restrict__ ws_gh,
    float* __restrict__ ws_sc, u32* __restrict__ bars,
    float* __restrict__ outT) {
  const int k = blockIdx.x;        // 0..255
  const int tid = threadIdx.x;
  const int lane = tid & 63;
  const int wv = tid >> 6;
  const int r0 = k * 8;            // S1 row base and vt row base
  const int bP = k >> 4;           // S2b/S3 batch
  const int i0 = (k & 15) * 32;    // S2b/S3 h-slice

  __shared__ u16 P_lds[128][96];   // 24 KB, bf16
  __shared__ float s_lds[128];
  __shared__ float p_lds[128];
  __shared__ float gi_l[96];
  __shared__ float gh_l[96];

  // ---- step-invariant preloads (registers) ----
  float Wreg[8][8];   // my lane's K-slice of my 8 S1 weight rows
  float Wbias[8];
#pragma unroll
  for (int rr = 0; rr < 8; ++rr) {
    int r = r0 + rr;
    const float* wp = (r < 512) ? (Wq + (size_t)r * 512) : (Whh + (size_t)(r - 512) * 512);
    const float4* w4 = (const float4*)(wp + (lane << 3));
    float4 a = w4[0], b = w4[1];
    Wreg[rr][0] = a.x; Wreg[rr][1] = a.y; Wreg[rr][2] = a.z; Wreg[rr][3] = a.w;
    Wreg[rr][4] = b.x; Wreg[rr][5] = b.y; Wreg[rr][6] = b.z; Wreg[rr][7] = b.w;
    Wbias[rr] = (r < 512) ? bq[r] : bhh[r - 512];
  }
  float vtreg[2][8];
  int mval[2];
#pragma unroll
  for (int u = 0; u < 2; ++u) {
    int m = r0 + (wv << 1) + u;
    const float4* v4 = (const float4*)(ws_vt + (size_t)m * 512 + (lane << 3));
    float4 a = v4[0], b = v4[1];
    vtreg[u][0] = a.x; vtreg[u][1] = a.y; vtreg[u][2] = a.z; vtreg[u][3] = a.w;
    vtreg[u][4] = b.x; vtreg[u][5] = b.y; vtreg[u][6] = b.z; vtreg[u][7] = b.w;
    mval[u] = mask[m];
  }
  float Wc_l[8];
  {
    const float4* c4 = (const float4*)(Wc + (lane << 3));
    float4 a = c4[0], b = c4[1];
    Wc_l[0] = a.x; Wc_l[1] = a.y; Wc_l[2] = a.z; Wc_l[3] = a.w;
    Wc_l[4] = b.x; Wc_l[5] = b.y; Wc_l[6] = b.z; Wc_l[7] = b.w;
  }
  const float bc0 = bc[0];
  // P slice -> LDS (bf16)
  for (int idx = tid; idx < 128 * 96; idx += 256) {
    int t = idx / 96; int j = idx - t * 96;
    int col = (j >> 5) * 512 + i0 + (j & 31);
    P_lds[t][j] = f2bf(ws_P[(size_t)((bP << 7) + t) * 1536 + col]);
  }
  __syncthreads();

  u32 phase = 0;
  for (int s = 0; s < STEPS; ++s) {
    const float* hbase = (s == 0) ? h0 : (ws_hall + (size_t)(s - 1) * (16 * 512));

    // ---- S1: q rows (r<512) / gh rows, all 16 b ----
#pragma unroll
    for (int bb = 0; bb < 4; ++bb) {
      int b = (wv << 2) | bb;
      const float* hp = hbase + (b << 9) + (lane << 3);
      float4 ha = *(const float4*)hp;
      float4 hb = *(const float4*)(hp + 4);
#pragma unroll
      for (int rr = 0; rr < 8; ++rr) {
        float p = Wreg[rr][0] * ha.x + Wreg[rr][1] * ha.y + Wreg[rr][2] * ha.z + Wreg[rr][3] * ha.w
                + Wreg[rr][4] * hb.x + Wreg[rr][5] * hb.y + Wreg[rr][6] * hb.z + Wreg[rr][7] * hb.w;
        p = wred(p);
        if (lane == 0) {
          int r = r0 + rr;
          float val = p + Wbias[rr];
          if (r < 512) ws_q[(b << 9) + r] = val;
          else         ws_gh[b * 1536 + (r - 512)] = val;
        }
      }
    }
    gbar(bars, ++phase);

    // ---- S2a: scores for my 8 (b,t) rows ----
#pragma unroll
    for (int u = 0; u < 2; ++u) {
      int m = r0 + (wv << 1) + u;
      int b = m >> 7;
      const float* qp = ws_q + (b << 9) + (lane << 3);
      float4 qa = *(const float4*)qp;
      float4 qb = *(const float4*)(qp + 4);
      float acc;
      acc  = Wc_l[0] * tanhf(qa.x + vtreg[u][0]);
      acc += Wc_l[1] * tanhf(qa.y + vtreg[u][1]);
      acc += Wc_l[2] * tanhf(qa.z + vtreg[u][2]);
      acc += Wc_l[3] * tanhf(qa.w + vtreg[u][3]);
      acc += Wc_l[4] * tanhf(qb.x + vtreg[u][4]);
      acc += Wc_l[5] * tanhf(qb.y + vtreg[u][5]);
      acc += Wc_l[6] * tanhf(qb.z + vtreg[u][6]);
      acc += Wc_l[7] * tanhf(qb.w + vtreg[u][7]);
      acc = wred(acc);
      if (lane == 0) {
        float sc = acc + bc0;
        if (mval[u] == 0) sc = -3.4028234663852886e+38f;
        ws_sc[m] = sc;
      }
    }
    gbar(bars, ++phase);

    // ---- S2b/S3: softmax (redundant per block) + gates_ctx + GRU update for my slice ----
    if (tid < 128) s_lds[tid] = ws_sc[(bP << 7) + tid];
    __syncthreads();
    float vm = fmaxf(s_lds[lane], s_lds[64 + lane]);
#pragma unroll
    for (int mo = 32; mo > 0; mo >>= 1) vm = fmaxf(vm, __shfl_xor(vm, mo, 64));
    if (tid < 128) p_lds[tid] = expf(s_lds[tid] - vm);
    __syncthreads();
    float vs = p_lds[lane] + p_lds[64 + lane];
#pragma unroll
    for (int mo = 32; mo > 0; mo >>= 1) vs += __shfl_xor(vs, mo, 64);
    float rsum = 1.0f / vs;
    if (tid < 96) {
      int jg = (tid >> 5) * 512 + i0 + (tid & 31);
      float acc = 0.f;
#pragma unroll 8
      for (int t = 0; t < 128; ++t) acc += p_lds[t] * bf2f(P_lds[t][tid]);
      gi_l[tid] = ws_gix[(size_t)((s << 4) + bP) * 1536 + jg] + acc * rsum;
      gh_l[tid] = ws_gh[bP * 1536 + jg];
    }
    __syncthreads();
    if (tid < 32) {
      int i = i0 + tid;
      float rg = 1.f / (1.f + expf(-(gi_l[tid] + gh_l[tid])));
      float zg = 1.f / (1.f + expf(-(gi_l[32 + tid] + gh_l[32 + tid])));
      float ng = tanhf(gi_l[64 + tid] + rg * gh_l[64 + tid]);
      float hold = hbase[(bP << 9) + i];
      float hn = (1.f - zg) * ng + zg * hold;
      ws_hall[(size_t)((s << 4) + bP) * 512 + i] = hn;
    }
    gbar(bars, ++phase);
  }

  // hT output
  if (k < 16) {
    for (int i = tid; i < 512; i += 256)
      outT[(k << 9) + i] = ws_hall[(size_t)(126 * 16 + k) * 512 + i];
  }
}

// ---------------- launch ----------------
extern "C" void kernel_launch(void* const* d_in, const int* in_sizes, int n_in,
                              void* d_out, int out_size, void* d_ws, size_t ws_size,
                              hipStream_t stream) {
  const float* enc  = (const float*)d_in[0];
  const float* ehid = (const float*)d_in[1];
  const int*   mask = (const int*)d_in[2];
  const int*   tgt  = (const int*)d_in[3];
  const float* emb  = (const float*)d_in[4];
  const float* Wq   = (const float*)d_in[5];
  const float* bq   = (const float*)d_in[6];
  const float* Wv   = (const float*)d_in[7];
  const float* bv   = (const float*)d_in[8];
  const float* Wc   = (const float*)d_in[9];
  const float* bc   = (const float*)d_in[10];
  const float* Wih  = (const float*)d_in[11];
  const float* Whh  = (const float*)d_in[12];
  const float* bih  = (const float*)d_in[13];
  const float* bhh  = (const float*)d_in[14];
  const float* Wo   = (const float*)d_in[15];
  const float* bo   = (const float*)d_in[16];

  float* out = (float*)d_out;
  float* ws  = (float*)d_ws;
  float* vt   = ws + OFF_VT;
  float* P    = ws + OFF_P;
  float* gix  = ws + OFF_GIX;
  float* hall = ws + OFF_HALL;
  float* q    = ws + OFF_Q;
  float* gh   = ws + OFF_GH;
  float* sc   = ws + OFF_SC;
  u32*   bars = (u32*)(ws + OFF_BAR);
  u16* A_enc = (u16*)(ws + OFF_AENC);
  u16* A_emb = (u16*)(ws + OFF_AEMB);
  u16* A_h   = (u16*)(ws + OFF_AH);
  u16* B_wv  = (u16*)(ws + OFF_BWV);
  u16* B_wi1 = (u16*)(ws + OFF_BWIH1);
  u16* B_wi2 = (u16*)(ws + OFF_BWIH2);
  u16* B_wo  = (u16*)(ws + OFF_BWO);

  k_init<<<2000, 256, 0, stream>>>(out, bars);
  k_f2bf<<<4096, 256, 0, stream>>>(enc, A_enc, 1048576);
  k_f2bf<<<1024, 256, 0, stream>>>(Wv, B_wv, 262144);
  k_f2bf_sub<<<3072, 256, 0, stream>>>(Wih, B_wi1, 786432, 1024, 0);
  k_f2bf_sub<<<3072, 256, 0, stream>>>(Wih, B_wi2, 786432, 1024, 512);
  k_f2bf<<<64000, 256, 0, stream>>>(Wo, B_wo, 16384000);
  k_gather<<<4064, 256, 0, stream>>>(emb, tgt, A_emb, 1040384);

  // vt = enc @ Wv.T + bv            [2048 x 512]
  gemm_bf16<<<dim3(4, 16), 256, 0, stream>>>(A_enc, B_wv, bv, vt, 512, 0);
  // P  = enc @ Wih[:,H:].T          [2048 x 1536]
  gemm_bf16<<<dim3(12, 16), 256, 0, stream>>>(A_enc, B_wi2, nullptr, P, 1536, 0);
  // gi_x = emb[toks] @ Wih[:,:H].T + bih   [2032 x 1536]
  gemm_bf16<<<dim3(12, 16), 256, 0, stream>>>(A_emb, B_wi1, bih, gix, 1536, 0);

  seq_kernel<<<256, 256, 0, stream>>>(Wq, bq, Wc, bc, Whh, bhh,
                                      ehid, mask, vt, P, gix, hall, q, gh, sc, bars,
                                      out + 65536000);

  k_f2bf<<<4064, 256, 0, stream>>>(hall, A_h, 1040384);
  // logits = h_all @ Wo.T + bo -> out[:,1:,:]
  gemm_bf16<<<dim3(250, 16), 256, 0, stream>>>(A_h, B_wo, bo, out, 32000, 1);
}

// Round 2
// 5405.774 us; speedup vs baseline: 2.7338x; 2.7338x over previous
//
#include <hip/hip_runtime.h>

typedef unsigned short u16;
typedef unsigned int u32;
typedef short bf16x8 __attribute__((ext_vector_type(8)));
typedef float f32x4 __attribute__((ext_vector_type(4)));

#define B_ 16
#define T_ 128
#define H_ 512
#define V_ 32000
#define G3 1536
#define STEPS 127

// ---------------- ws layout (float units) ----------------
#define OFF_VT    0u            // [2048][512]  m=b*128+t
#define OFF_P     1048576u      // [2048][1536] m=b*128+t
#define OFF_GIX   4194304u      // [2048][1536] m=s*16+b
#define OFF_HALL  7340032u      // [2048][512]  m=s*16+b
#define OFF_Q     8388608u      // [16][512]
#define OFF_GH    8396800u      // [16][1536]
#define OFF_SC    8421376u      // [16][128]
#define OFF_BAR   8423424u      // 256 u32, compact (1 cache-line group)
#define OFF_AENC  8431616u      // bf16 [2048][512]
#define OFF_AEMB  8955904u
#define OFF_AH    9480192u
#define OFF_BWV   10004480u     // bf16 [512][512]
#define OFF_BWIH1 10135552u     // bf16 [1536][512]
#define OFF_BWIH2 10528768u
#define OFF_BWO   10921984u     // bf16 [32000][512]

__device__ __forceinline__ u16 f2bf(float f) {
  union { float f; u32 u; } x; x.f = f;
  u32 r = x.u + 0x7fffu + ((x.u >> 16) & 1u);
  return (u16)(r >> 16);
}
__device__ __forceinline__ float bf2f(u16 u) {
  union { u32 u; float f; } x; x.u = ((u32)u) << 16;
  return x.f;
}
__device__ __forceinline__ float wred(float v) {
#pragma unroll
  for (int off = 32; off > 0; off >>= 1) v += __shfl_down(v, off, 64);
  return v; // valid in lane 0
}

// ---------------- small utility kernels ----------------
__global__ void k_init(float* __restrict__ out, u32* __restrict__ bars) {
  int idx = blockIdx.x * 256 + threadIdx.x;
  if (idx < 512000) {            // out[:,0,:] = 0
    int b = idx / 32000; int v = idx - b * 32000;
    out[(size_t)b * 4096000 + v] = 0.f;
  }
  if (idx < 256) bars[idx] = 0u;
}

__global__ void k_f2bf(const float* __restrict__ src, u16* __restrict__ dst, int n) {
  int idx = blockIdx.x * 256 + threadIdx.x;
  if (idx < n) dst[idx] = f2bf(src[idx]);
}

// take 512-wide column slice [off, off+512) of rows with leading dim ld
__global__ void k_f2bf_sub(const float* __restrict__ src, u16* __restrict__ dst,
                           int n, int ld, int off) {
  int idx = blockIdx.x * 256 + threadIdx.x;
  if (idx < n) {
    int r = idx >> 9, c = idx & 511;
    dst[idx] = f2bf(src[(size_t)r * ld + off + c]);
  }
}

// A_emb[m= s*16+b][c] = bf16(emb[tok(b,s)][c]), tok = s==0 ? BOS(1) : target[b][s]
__global__ void k_gather(const float* __restrict__ emb, const int* __restrict__ tgt,
                         u16* __restrict__ dst, int n) {
  int idx = blockIdx.x * 256 + threadIdx.x;
  if (idx < n) {
    int m = idx >> 9, c = idx & 511;
    int b = m & 15, s = m >> 4;
    int tok = (s == 0) ? 1 : tgt[b * 128 + s];
    dst[idx] = f2bf(emb[(size_t)tok * 512 + c]);
  }
}

// ---------------- bf16 MFMA GEMM: C[m][n] = sum_k A[m][k]*B[n][k] + bias[n] ----------------
// A: [gridDim.y*128][512] bf16, B: [N][512] bf16. mode 0: C[m*ldc+n]. mode 1: decoder remap.
__global__ __launch_bounds__(256) void gemm_bf16(
    const u16* __restrict__ A, const u16* __restrict__ Bm,
    const float* __restrict__ bias, float* __restrict__ C,
    int ldc, int mode) {
  __shared__ u16 As[128 * 32];
  __shared__ u16 Bs[128 * 32];
  const int tid = threadIdx.x;
  const int lane = tid & 63;
  const int wave = tid >> 6;
  const int lr = lane & 15;
  const int quad = lane >> 4;
  const int wm = (wave >> 1) * 64;
  const int wn = (wave & 1) * 64;
  const int bm = blockIdx.y * 128;
  const int bn = blockIdx.x * 128;
  const int srow = tid >> 1;          // 0..127
  const int shalf = (tid & 1) * 16;   // 0 or 16

  f32x4 acc[4][4];
#pragma unroll
  for (int i = 0; i < 4; ++i)
#pragma unroll
    for (int j = 0; j < 4; ++j) acc[i][j] = (f32x4){0.f, 0.f, 0.f, 0.f};

  for (int kt = 0; kt < 16; ++kt) {
    const u16* gA = A + (size_t)(bm + srow) * 512 + kt * 32 + shalf;
    const u16* gB = Bm + (size_t)(bn + srow) * 512 + kt * 32 + shalf;
    uint4 a0 = *(const uint4*)gA;
    uint4 a1 = *(const uint4*)(gA + 8);
    uint4 b0 = *(const uint4*)gB;
    uint4 b1 = *(const uint4*)(gB + 8);
    __syncthreads();
    *(uint4*)&As[srow * 32 + shalf] = a0;
    *(uint4*)&As[srow * 32 + shalf + 8] = a1;
    *(uint4*)&Bs[srow * 32 + shalf] = b0;
    *(uint4*)&Bs[srow * 32 + shalf + 8] = b1;
    __syncthreads();
    bf16x8 af[4], bf[4];
#pragma unroll
    for (int i = 0; i < 4; ++i)
      af[i] = *(const bf16x8*)&As[(wm + i * 16 + lr) * 32 + quad * 8];
#pragma unroll
    for (int j = 0; j < 4; ++j)
      bf[j] = *(const bf16x8*)&Bs[(wn + j * 16 + lr) * 32 + quad * 8];
#pragma unroll
    for (int i = 0; i < 4; ++i)
#pragma unroll
      for (int j = 0; j < 4; ++j)
        acc[i][j] = __builtin_amdgcn_mfma_f32_16x16x32_bf16(af[i], bf[j], acc[i][j], 0, 0, 0);
  }

#pragma unroll
  for (int j = 0; j < 4; ++j) {
    int ng = bn + wn + j * 16 + lr;
    float bv = bias ? bias[ng] : 0.f;
#pragma unroll
    for (int i = 0; i < 4; ++i) {
      int mg0 = bm + wm + i * 16 + quad * 4;
#pragma unroll
      for (int r = 0; r < 4; ++r) {
        int mg = mg0 + r;
        float v = acc[i][j][r] + bv;
        if (mode == 0) {
          C[(size_t)mg * ldc + ng] = v;
        } else {
          if (mg < 2032) {
            int s = mg >> 4, b = mg & 15;
            C[(size_t)((b << 7) + s + 1) * 32000 + ng] = v;
          }
        }
      }
    }
  }
}

// ---------------- sequential recurrence (persistent, manual grid barrier) ----------------
// Fast grid barrier: ONE release fence (wbl2) + ONE acquire fence (inv) per
// barrier, from wave 0 only; polls are RELAXED agent-scope atomic loads
// (sc1 coherent, no per-iteration buffer_inv). bars is compact u32[256] so
// wave 0 covers all slots with 4 loads/lane = 4 cache lines.
__device__ __forceinline__ void gbar(u32* bars, u32 phase) {
  __syncthreads();   // compiler emits s_waitcnt vmcnt(0) before s_barrier -> all waves' stores in L2
  if (threadIdx.x < 64) {
    __builtin_amdgcn_fence(__ATOMIC_RELEASE, "agent");   // wbl2: publish our stores
    if (threadIdx.x == 0)
      __hip_atomic_store(&bars[blockIdx.x], phase, __ATOMIC_RELAXED, __HIP_MEMORY_SCOPE_AGENT);
    const int t = threadIdx.x;
    for (;;) {
      u32 a = __hip_atomic_load(&bars[t],       __ATOMIC_RELAXED, __HIP_MEMORY_SCOPE_AGENT);
      u32 b = __hip_atomic_load(&bars[t + 64],  __ATOMIC_RELAXED, __HIP_MEMORY_SCOPE_AGENT);
      u32 c = __hip_atomic_load(&bars[t + 128], __ATOMIC_RELAXED, __HIP_MEMORY_SCOPE_AGENT);
      u32 d = __hip_atomic_load(&bars[t + 192], __ATOMIC_RELAXED, __HIP_MEMORY_SCOPE_AGENT);
      u32 m = min(min(a, b), min(c, d));
      if (__all(m >= phase)) break;
      __builtin_amdgcn_s_sleep(4);
    }
    __builtin_amdgcn_fence(__ATOMIC_ACQUIRE, "agent");   // inv: drop stale L1/L2 lines
  }
  __syncthreads();
}

__global__ __launch_bounds__(256, 1) void seq_kernel(
    const float* __restrict__ Wq, const float* __restrict__ bq,
    const float* __restrict__ Wc, const float* __restrict__ bc,
    const float* __restrict__ Whh, const float* __restrict__ bhh,
    const float* __restrict__ h0, const int* __restrict__ mask,
    float* __restrict__ ws_vt, float* __restrict__ ws_P,
    float* __restrict__ ws_gix, float* __restrict__ ws_hall,
    float* __restrict__ ws_q, float* __restrict__ ws_gh,
    float* __restrict__ ws_sc, u32* __restrict__ bars,
    float* __restrict__ outT) {
  const int k = blockIdx.x;        // 0..255
  const int tid = threadIdx.x;
  const int lane = tid & 63;
  const int wv = tid >> 6;
  const int r0 = k * 8;            // S1 row base and vt row base
  const int bP = k >> 4;           // S2b/S3 batch
  const int i0 = (k & 15) * 32;    // S2b/S3 h-slice

  __shared__ u16 P_lds[128][96];   // 24 KB, bf16
  __shared__ float s_lds[128];
  __shared__ float p_lds[128];
  __shared__ float gi_l[96];
  __shared__ float gh_l[96];

  // ---- step-invariant preloads (registers) ----
  float Wreg[8][8];   // my lane's K-slice of my 8 S1 weight rows
  float Wbias[8];
#pragma unroll
  for (int rr = 0; rr < 8; ++rr) {
    int r = r0 + rr;
    const float* wp = (r < 512) ? (Wq + (size_t)r * 512) : (Whh + (size_t)(r - 512) * 512);
    const float4* w4 = (const float4*)(wp + (lane << 3));
    float4 a = w4[0], b = w4[1];
    Wreg[rr][0] = a.x; Wreg[rr][1] = a.y; Wreg[rr][2] = a.z; Wreg[rr][3] = a.w;
    Wreg[rr][4] = b.x; Wreg[rr][5] = b.y; Wreg[rr][6] = b.z; Wreg[rr][7] = b.w;
    Wbias[rr] = (r < 512) ? bq[r] : bhh[r - 512];
  }
  float vtreg[2][8];
  int mval[2];
#pragma unroll
  for (int u = 0; u < 2; ++u) {
    int m = r0 + (wv << 1) + u;
    const float4* v4 = (const float4*)(ws_vt + (size_t)m * 512 + (lane << 3));
    float4 a = v4[0], b = v4[1];
    vtreg[u][0] = a.x; vtreg[u][1] = a.y; vtreg[u][2] = a.z; vtreg[u][3] = a.w;
    vtreg[u][4] = b.x; vtreg[u][5] = b.y; vtreg[u][6] = b.z; vtreg[u][7] = b.w;
    mval[u] = mask[m];
  }
  float Wc_l[8];
  {
    const float4* c4 = (const float4*)(Wc + (lane << 3));
    float4 a = c4[0], b = c4[1];
    Wc_l[0] = a.x; Wc_l[1] = a.y; Wc_l[2] = a.z; Wc_l[3] = a.w;
    Wc_l[4] = b.x; Wc_l[5] = b.y; Wc_l[6] = b.z; Wc_l[7] = b.w;
  }
  const float bc0 = bc[0];
  // P slice -> LDS (bf16)
  for (int idx = tid; idx < 128 * 96; idx += 256) {
    int t = idx / 96; int j = idx - t * 96;
    int col = (j >> 5) * 512 + i0 + (j & 31);
    P_lds[t][j] = f2bf(ws_P[(size_t)((bP << 7) + t) * 1536 + col]);
  }
  __syncthreads();

  u32 phase = 0;
  for (int s = 0; s < STEPS; ++s) {
    const float* hbase = (s == 0) ? h0 : (ws_hall + (size_t)(s - 1) * (16 * 512));

    // ---- S1: q rows (r<512) / gh rows, all 16 b ----
#pragma unroll
    for (int bb = 0; bb < 4; ++bb) {
      int b = (wv << 2) | bb;
      const float* hp = hbase + (b << 9) + (lane << 3);
      float4 ha = *(const float4*)hp;
      float4 hb = *(const float4*)(hp + 4);
#pragma unroll
      for (int rr = 0; rr < 8; ++rr) {
        float p = Wreg[rr][0] * ha.x + Wreg[rr][1] * ha.y + Wreg[rr][2] * ha.z + Wreg[rr][3] * ha.w
                + Wreg[rr][4] * hb.x + Wreg[rr][5] * hb.y + Wreg[rr][6] * hb.z + Wreg[rr][7] * hb.w;
        p = wred(p);
        if (lane == 0) {
          int r = r0 + rr;
          float val = p + Wbias[rr];
          if (r < 512) ws_q[(b << 9) + r] = val;
          else         ws_gh[b * 1536 + (r - 512)] = val;
        }
      }
    }
    gbar(bars, ++phase);

    // ---- S2a: scores for my 8 (b,t) rows ----
#pragma unroll
    for (int u = 0; u < 2; ++u) {
      int m = r0 + (wv << 1) + u;
      int b = m >> 7;
      const float* qp = ws_q + (b << 9) + (lane << 3);
      float4 qa = *(const float4*)qp;
      float4 qb = *(const float4*)(qp + 4);
      float acc;
      acc  = Wc_l[0] * tanhf(qa.x + vtreg[u][0]);
      acc += Wc_l[1] * tanhf(qa.y + vtreg[u][1]);
      acc += Wc_l[2] * tanhf(qa.z + vtreg[u][2]);
      acc += Wc_l[3] * tanhf(qa.w + vtreg[u][3]);
      acc += Wc_l[4] * tanhf(qb.x + vtreg[u][4]);
      acc += Wc_l[5] * tanhf(qb.y + vtreg[u][5]);
      acc += Wc_l[6] * tanhf(qb.z + vtreg[u][6]);
      acc += Wc_l[7] * tanhf(qb.w + vtreg[u][7]);
      acc = wred(acc);
      if (lane == 0) {
        float sc = acc + bc0;
        if (mval[u] == 0) sc = -3.4028234663852886e+38f;
        ws_sc[m] = sc;
      }
    }
    gbar(bars, ++phase);

    // ---- S2b/S3: softmax (redundant per block) + gates_ctx + GRU update for my slice ----
    if (tid < 128) s_lds[tid] = ws_sc[(bP << 7) + tid];
    __syncthreads();
    float vm = fmaxf(s_lds[lane], s_lds[64 + lane]);
#pragma unroll
    for (int mo = 32; mo > 0; mo >>= 1) vm = fmaxf(vm, __shfl_xor(vm, mo, 64));
    if (tid < 128) p_lds[tid] = expf(s_lds[tid] - vm);
    __syncthreads();
    float vs = p_lds[lane] + p_lds[64 + lane];
#pragma unroll
    for (int mo = 32; mo > 0; mo >>= 1) vs += __shfl_xor(vs, mo, 64);
    float rsum = 1.0f / vs;
    if (tid < 96) {
      int jg = (tid >> 5) * 512 + i0 + (tid & 31);
      float acc = 0.f;
#pragma unroll 8
      for (int t = 0; t < 128; ++t) acc += p_lds[t] * bf2f(P_lds[t][tid]);
      gi_l[tid] = ws_gix[(size_t)((s << 4) + bP) * 1536 + jg] + acc * rsum;
      gh_l[tid] = ws_gh[bP * 1536 + jg];
    }
    __syncthreads();
    if (tid < 32) {
      int i = i0 + tid;
      float rg = 1.f / (1.f + expf(-(gi_l[tid] + gh_l[tid])));
      float zg = 1.f / (1.f + expf(-(gi_l[32 + tid] + gh_l[32 + tid])));
      float ng = tanhf(gi_l[64 + tid] + rg * gh_l[64 + tid]);
      float hold = hbase[(bP << 9) + i];
      float hn = (1.f - zg) * ng + zg * hold;
      ws_hall[(size_t)((s << 4) + bP) * 512 + i] = hn;
    }
    gbar(bars, ++phase);
  }

  // hT output
  if (k < 16) {
    for (int i = tid; i < 512; i += 256)
      outT[(k << 9) + i] = ws_hall[(size_t)(126 * 16 + k) * 512 + i];
  }
}

// ---------------- launch ----------------
extern "C" void kernel_launch(void* const* d_in, const int* in_sizes, int n_in,
                              void* d_out, int out_size, void* d_ws, size_t ws_size,
                              hipStream_t stream) {
  const float* enc  = (const float*)d_in[0];
  const float* ehid = (const float*)d_in[1];
  const int*   mask = (const int*)d_in[2];
  const int*   tgt  = (const int*)d_in[3];
  const float* emb  = (const float*)d_in[4];
  const float* Wq   = (const float*)d_in[5];
  const float* bq   = (const float*)d_in[6];
  const float* Wv   = (const float*)d_in[7];
  const float* bv   = (const float*)d_in[8];
  const float* Wc   = (const float*)d_in[9];
  const float* bc   = (const float*)d_in[10];
  const float* Wih  = (const float*)d_in[11];
  const float* Whh  = (const float*)d_in[12];
  const float* bih  = (const float*)d_in[13];
  const float* bhh  = (const float*)d_in[14];
  const float* Wo   = (const float*)d_in[15];
  const float* bo   = (const float*)d_in[16];

  float* out = (float*)d_out;
  float* ws  = (float*)d_ws;
  float* vt   = ws + OFF_VT;
  float* P    = ws + OFF_P;
  float* gix  = ws + OFF_GIX;
  float* hall = ws + OFF_HALL;
  float* q    = ws + OFF_Q;
  float* gh   = ws + OFF_GH;
  float* sc   = ws + OFF_SC;
  u32*   bars = (u32*)(ws + OFF_BAR);
  u16* A_enc = (u16*)(ws + OFF_AENC);
  u16* A_emb = (u16*)(ws + OFF_AEMB);
  u16* A_h   = (u16*)(ws + OFF_AH);
  u16* B_wv  = (u16*)(ws + OFF_BWV);
  u16* B_wi1 = (u16*)(ws + OFF_BWIH1);
  u16* B_wi2 = (u16*)(ws + OFF_BWIH2);
  u16* B_wo  = (u16*)(ws + OFF_BWO);

  k_init<<<2000, 256, 0, stream>>>(out, bars);
  k_f2bf<<<4096, 256, 0, stream>>>(enc, A_enc, 1048576);
  k_f2bf<<<1024, 256, 0, stream>>>(Wv, B_wv, 262144);
  k_f2bf_sub<<<3072, 256, 0, stream>>>(Wih, B_wi1, 786432, 1024, 0);
  k_f2bf_sub<<<3072, 256, 0, stream>>>(Wih, B_wi2, 786432, 1024, 512);
  k_f2bf<<<64000, 256, 0, stream>>>(Wo, B_wo, 16384000);
  k_gather<<<4064, 256, 0, stream>>>(emb, tgt, A_emb, 1040384);

  // vt = enc @ Wv.T + bv            [2048 x 512]
  gemm_bf16<<<dim3(4, 16), 256, 0, stream>>>(A_enc, B_wv, bv, vt, 512, 0);
  // P  = enc @ Wih[:,H:].T          [2048 x 1536]
  gemm_bf16<<<dim3(12, 16), 256, 0, stream>>>(A_enc, B_wi2, nullptr, P, 1536, 0);
  // gi_x = emb[toks] @ Wih[:,:H].T + bih   [2032 x 1536]
  gemm_bf16<<<dim3(12, 16), 256, 0, stream>>>(A_emb, B_wi1, bih, gix, 1536, 0);

  seq_kernel<<<256, 256, 0, stream>>>(Wq, bq, Wc, bc, Whh, bhh,
                                      ehid, mask, vt, P, gix, hall, q, gh, sc, bars,
                                      out + 65536000);

  k_f2bf<<<4064, 256, 0, stream>>>(hall, A_h, 1040384);
  // logits = h_all @ Wo.T + bo -> out[:,1:,:]
  gemm_bf16<<<dim3(250, 16), 256, 0, stream>>>(A_h, B_wo, bo, out, 32000, 1);
}

// Round 3
// 4295.430 us; speedup vs baseline: 3.4404x; 1.2585x over previous
//
#include <hip/hip_runtime.h>

typedef unsigned short u16;
typedef unsigned int u32;
typedef short bf16x8 __attribute__((ext_vector_type(8)));
typedef float f32x4 __attribute__((ext_vector_type(4)));

#define B_ 16
#define T_ 128
#define H_ 512
#define V_ 32000
#define G3 1536
#define STEPS 127

// ---------------- ws layout (float units) ----------------
#define OFF_VT    0u            // [2048][512]  m=b*128+t
#define OFF_P     1048576u      // [2048][1536] m=b*128+t
#define OFF_GIX   4194304u      // [2048][1536] m=s*16+b
#define OFF_HALL  7340032u      // [2048][512]  m=s*16+b
#define OFF_Q     8388608u      // [16][512]
#define OFF_GH    8396800u      // [16][1536]
#define OFF_SC    8421376u      // [16][128]
#define OFF_BAR   8423424u      // 256 u32, compact
#define OFF_AENC  8431616u      // bf16 [2048][512]
#define OFF_AEMB  8955904u
#define OFF_AH    9480192u
#define OFF_BWV   10004480u     // bf16 [512][512]
#define OFF_BWIH1 10135552u     // bf16 [1536][512]
#define OFF_BWIH2 10528768u
#define OFF_BWO   10921984u     // bf16 [32000][512]

__device__ __forceinline__ u16 f2bf(float f) {
  union { float f; u32 u; } x; x.f = f;
  u32 r = x.u + 0x7fffu + ((x.u >> 16) & 1u);
  return (u16)(r >> 16);
}
__device__ __forceinline__ float bf2f(u16 u) {
  union { u32 u; float f; } x; x.u = ((u32)u) << 16;
  return x.f;
}
__device__ __forceinline__ float wred(float v) {
#pragma unroll
  for (int off = 32; off > 0; off >>= 1) v += __shfl_down(v, off, 64);
  return v; // valid in lane 0
}

// MALL-coherent (sc0 sc1) scalar exchange: relaxed agent-scope atomics bypass
// stale L1/per-XCD-L2 and are serialized at the Infinity Cache. No fences.
__device__ __forceinline__ void st_sys(float* p, float v) {
  __hip_atomic_store(p, v, __ATOMIC_RELAXED, __HIP_MEMORY_SCOPE_AGENT);
}
__device__ __forceinline__ float ld_sys(const float* p) {
  return __hip_atomic_load(p, __ATOMIC_RELAXED, __HIP_MEMORY_SCOPE_AGENT);
}

// ---------------- small utility kernels ----------------
__global__ void k_init(float* __restrict__ out, u32* __restrict__ bars) {
  int idx = blockIdx.x * 256 + threadIdx.x;
  if (idx < 512000) {            // out[:,0,:] = 0
    int b = idx / 32000; int v = idx - b * 32000;
    out[(size_t)b * 4096000 + v] = 0.f;
  }
  if (idx < 256) bars[idx] = 0u;
}

__global__ void k_f2bf(const float* __restrict__ src, u16* __restrict__ dst, int n) {
  int idx = blockIdx.x * 256 + threadIdx.x;
  if (idx < n) dst[idx] = f2bf(src[idx]);
}

// take 512-wide column slice [off, off+512) of rows with leading dim ld
__global__ void k_f2bf_sub(const float* __restrict__ src, u16* __restrict__ dst,
                           int n, int ld, int off) {
  int idx = blockIdx.x * 256 + threadIdx.x;
  if (idx < n) {
    int r = idx >> 9, c = idx & 511;
    dst[idx] = f2bf(src[(size_t)r * ld + off + c]);
  }
}

// A_emb[m= s*16+b][c] = bf16(emb[tok(b,s)][c]), tok = s==0 ? BOS(1) : target[b][s]
__global__ void k_gather(const float* __restrict__ emb, const int* __restrict__ tgt,
                         u16* __restrict__ dst, int n) {
  int idx = blockIdx.x * 256 + threadIdx.x;
  if (idx < n) {
    int m = idx >> 9, c = idx & 511;
    int b = m & 15, s = m >> 4;
    int tok = (s == 0) ? 1 : tgt[b * 128 + s];
    dst[idx] = f2bf(emb[(size_t)tok * 512 + c]);
  }
}

// ---------------- bf16 MFMA GEMM: C[m][n] = sum_k A[m][k]*B[n][k] + bias[n] ----------------
__global__ __launch_bounds__(256) void gemm_bf16(
    const u16* __restrict__ A, const u16* __restrict__ Bm,
    const float* __restrict__ bias, float* __restrict__ C,
    int ldc, int mode) {
  __shared__ u16 As[128 * 32];
  __shared__ u16 Bs[128 * 32];
  const int tid = threadIdx.x;
  const int lane = tid & 63;
  const int wave = tid >> 6;
  const int lr = lane & 15;
  const int quad = lane >> 4;
  const int wm = (wave >> 1) * 64;
  const int wn = (wave & 1) * 64;
  const int bm = blockIdx.y * 128;
  const int bn = blockIdx.x * 128;
  const int srow = tid >> 1;          // 0..127
  const int shalf = (tid & 1) * 16;   // 0 or 16

  f32x4 acc[4][4];
#pragma unroll
  for (int i = 0; i < 4; ++i)
#pragma unroll
    for (int j = 0; j < 4; ++j) acc[i][j] = (f32x4){0.f, 0.f, 0.f, 0.f};

  for (int kt = 0; kt < 16; ++kt) {
    const u16* gA = A + (size_t)(bm + srow) * 512 + kt * 32 + shalf;
    const u16* gB = Bm + (size_t)(bn + srow) * 512 + kt * 32 + shalf;
    uint4 a0 = *(const uint4*)gA;
    uint4 a1 = *(const uint4*)(gA + 8);
    uint4 b0 = *(const uint4*)gB;
    uint4 b1 = *(const uint4*)(gB + 8);
    __syncthreads();
    *(uint4*)&As[srow * 32 + shalf] = a0;
    *(uint4*)&As[srow * 32 + shalf + 8] = a1;
    *(uint4*)&Bs[srow * 32 + shalf] = b0;
    *(uint4*)&Bs[srow * 32 + shalf + 8] = b1;
    __syncthreads();
    bf16x8 af[4], bf[4];
#pragma unroll
    for (int i = 0; i < 4; ++i)
      af[i] = *(const bf16x8*)&As[(wm + i * 16 + lr) * 32 + quad * 8];
#pragma unroll
    for (int j = 0; j < 4; ++j)
      bf[j] = *(const bf16x8*)&Bs[(wn + j * 16 + lr) * 32 + quad * 8];
#pragma unroll
    for (int i = 0; i < 4; ++i)
#pragma unroll
      for (int j = 0; j < 4; ++j)
        acc[i][j] = __builtin_amdgcn_mfma_f32_16x16x32_bf16(af[i], bf[j], acc[i][j], 0, 0, 0);
  }

#pragma unroll
  for (int j = 0; j < 4; ++j) {
    int ng = bn + wn + j * 16 + lr;
    float bv = bias ? bias[ng] : 0.f;
#pragma unroll
    for (int i = 0; i < 4; ++i) {
      int mg0 = bm + wm + i * 16 + quad * 4;
#pragma unroll
      for (int r = 0; r < 4; ++r) {
        int mg = mg0 + r;
        float v = acc[i][j][r] + bv;
        if (mode == 0) {
          C[(size_t)mg * ldc + ng] = v;
        } else {
          if (mg < 2032) {
            int s = mg >> 4, b = mg & 15;
            C[(size_t)((b << 7) + s + 1) * 32000 + ng] = v;
          }
        }
      }
    }
  }
}

// ---------------- fence-free grid barrier ----------------
// All cross-block data moves via sc0sc1 (MALL-coherent) atomics, so no
// buffer_wbl2 / buffer_inv is needed. Writer: vmcnt(0) drain -> flag store.
// Reader: poll flags. Data reads after the barrier use ld_sys (MALL-fresh).
__device__ __forceinline__ void gbar(u32* bars, u32 phase) {
  __syncthreads();   // compiler drains vmcnt before s_barrier -> all waves' sc1 stores at MALL
  if (threadIdx.x < 64) {
    asm volatile("s_waitcnt vmcnt(0)" ::: "memory");
    if (threadIdx.x == 0)
      __hip_atomic_store(&bars[blockIdx.x], phase, __ATOMIC_RELAXED, __HIP_MEMORY_SCOPE_AGENT);
    const int t = threadIdx.x;
    for (;;) {
      u32 a = __hip_atomic_load(&bars[t],       __ATOMIC_RELAXED, __HIP_MEMORY_SCOPE_AGENT);
      u32 b = __hip_atomic_load(&bars[t + 64],  __ATOMIC_RELAXED, __HIP_MEMORY_SCOPE_AGENT);
      u32 c = __hip_atomic_load(&bars[t + 128], __ATOMIC_RELAXED, __HIP_MEMORY_SCOPE_AGENT);
      u32 d = __hip_atomic_load(&bars[t + 192], __ATOMIC_RELAXED, __HIP_MEMORY_SCOPE_AGENT);
      u32 m0 = a < b ? a : b;
      u32 m1 = c < d ? c : d;
      u32 m = m0 < m1 ? m0 : m1;
      if (__all(m >= phase)) break;
      __builtin_amdgcn_s_sleep(1);
    }
  }
  asm volatile("" ::: "memory");
  __syncthreads();
}

__global__ __launch_bounds__(256, 1) void seq_kernel(
    const float* __restrict__ Wq, const float* __restrict__ bq,
    const float* __restrict__ Wc, const float* __restrict__ bc,
    const float* __restrict__ Whh, const float* __restrict__ bhh,
    const float* __restrict__ h0, const int* __restrict__ mask,
    float* __restrict__ ws_vt, float* __restrict__ ws_P,
    float* __restrict__ ws_gix, float* __restrict__ ws_hall,
    float* __restrict__ ws_q, float* __restrict__ ws_gh,
    float* __restrict__ ws_sc, u32* __restrict__ bars,
    float* __restrict__ outT) {
  const int k = blockIdx.x;        // 0..255
  const int tid = threadIdx.x;
  const int lane = tid & 63;
  const int wv = tid >> 6;
  const int r0 = k * 8;            // S1 row base and vt row base
  const int bP = k >> 4;           // S2b/S3 batch
  const int i0 = (k & 15) * 32;    // S2b/S3 h-slice

  __shared__ u16 P_lds[128][96];   // 24 KB, bf16
  __shared__ float s_lds[128];
  __shared__ float p_lds[128];
  __shared__ float gi_l[96];
  __shared__ float gh_l[96];

  // ---- step-invariant preloads (registers) ----
  float Wreg[8][8];   // my lane's K-slice of my 8 S1 weight rows
  float Wbias[8];
#pragma unroll
  for (int rr = 0; rr < 8; ++rr) {
    int r = r0 + rr;
    const float* wp = (r < 512) ? (Wq + (size_t)r * 512) : (Whh + (size_t)(r - 512) * 512);
    const float4* w4 = (const float4*)(wp + (lane << 3));
    float4 a = w4[0], b = w4[1];
    Wreg[rr][0] = a.x; Wreg[rr][1] = a.y; Wreg[rr][2] = a.z; Wreg[rr][3] = a.w;
    Wreg[rr][4] = b.x; Wreg[rr][5] = b.y; Wreg[rr][6] = b.z; Wreg[rr][7] = b.w;
    Wbias[rr] = (r < 512) ? bq[r] : bhh[r - 512];
  }
  float vtreg[2][8];
  int mval[2];
#pragma unroll
  for (int u = 0; u < 2; ++u) {
    int m = r0 + (wv << 1) + u;
    const float4* v4 = (const float4*)(ws_vt + (size_t)m * 512 + (lane << 3));
    float4 a = v4[0], b = v4[1];
    vtreg[u][0] = a.x; vtreg[u][1] = a.y; vtreg[u][2] = a.z; vtreg[u][3] = a.w;
    vtreg[u][4] = b.x; vtreg[u][5] = b.y; vtreg[u][6] = b.z; vtreg[u][7] = b.w;
    mval[u] = mask[m];
  }
  float Wc_l[8];
  {
    const float4* c4 = (const float4*)(Wc + (lane << 3));
    float4 a = c4[0], b = c4[1];
    Wc_l[0] = a.x; Wc_l[1] = a.y; Wc_l[2] = a.z; Wc_l[3] = a.w;
    Wc_l[4] = b.x; Wc_l[5] = b.y; Wc_l[6] = b.z; Wc_l[7] = b.w;
  }
  const float bc0 = bc[0];
  // P slice -> LDS (bf16)
  for (int idx = tid; idx < 128 * 96; idx += 256) {
    int t = idx / 96; int j = idx - t * 96;
    int col = (j >> 5) * 512 + i0 + (j & 31);
    P_lds[t][j] = f2bf(ws_P[(size_t)((bP << 7) + t) * 1536 + col]);
  }
  __syncthreads();

  u32 phase = 0;
  for (int s = 0; s < STEPS; ++s) {
    const float* hbase = (s == 0) ? h0 : (ws_hall + (size_t)(s - 1) * (16 * 512));

    // ---- S1: q rows (r<512) / gh rows, all 16 b ----
    float hv[4][8];
#pragma unroll
    for (int bb = 0; bb < 4; ++bb) {
      const float* hp = hbase + (((wv << 2) | bb) << 9) + (lane << 3);
#pragma unroll
      for (int e = 0; e < 8; ++e) hv[bb][e] = ld_sys(hp + e);
    }
#pragma unroll
    for (int bb = 0; bb < 4; ++bb) {
      int b = (wv << 2) | bb;
#pragma unroll
      for (int rr = 0; rr < 8; ++rr) {
        float p = Wreg[rr][0] * hv[bb][0] + Wreg[rr][1] * hv[bb][1]
                + Wreg[rr][2] * hv[bb][2] + Wreg[rr][3] * hv[bb][3]
                + Wreg[rr][4] * hv[bb][4] + Wreg[rr][5] * hv[bb][5]
                + Wreg[rr][6] * hv[bb][6] + Wreg[rr][7] * hv[bb][7];
        p = wred(p);
        if (lane == 0) {
          int r = r0 + rr;
          float val = p + Wbias[rr];
          if (r < 512) st_sys(&ws_q[(b << 9) + r], val);
          else         st_sys(&ws_gh[b * 1536 + (r - 512)], val);
        }
      }
    }
    gbar(bars, ++phase);

    // ---- S2a: scores for my 8 (b,t) rows ----
#pragma unroll
    for (int u = 0; u < 2; ++u) {
      int m = r0 + (wv << 1) + u;
      int b = m >> 7;
      const float* qp = ws_q + (b << 9) + (lane << 3);
      float qv[8];
#pragma unroll
      for (int e = 0; e < 8; ++e) qv[e] = ld_sys(qp + e);
      float acc;
      acc  = Wc_l[0] * tanhf(qv[0] + vtreg[u][0]);
      acc += Wc_l[1] * tanhf(qv[1] + vtreg[u][1]);
      acc += Wc_l[2] * tanhf(qv[2] + vtreg[u][2]);
      acc += Wc_l[3] * tanhf(qv[3] + vtreg[u][3]);
      acc += Wc_l[4] * tanhf(qv[4] + vtreg[u][4]);
      acc += Wc_l[5] * tanhf(qv[5] + vtreg[u][5]);
      acc += Wc_l[6] * tanhf(qv[6] + vtreg[u][6]);
      acc += Wc_l[7] * tanhf(qv[7] + vtreg[u][7]);
      acc = wred(acc);
      if (lane == 0) {
        float sc = acc + bc0;
        if (mval[u] == 0) sc = -3.4028234663852886e+38f;
        st_sys(&ws_sc[m], sc);
      }
    }
    gbar(bars, ++phase);

    // ---- S2b/S3: softmax (redundant per block) + gates_ctx + GRU update for my slice ----
    if (tid < 128) s_lds[tid] = ld_sys(&ws_sc[(bP << 7) + tid]);
    __syncthreads();
    float vm = fmaxf(s_lds[lane], s_lds[64 + lane]);
#pragma unroll
    for (int mo = 32; mo > 0; mo >>= 1) vm = fmaxf(vm, __shfl_xor(vm, mo, 64));
    if (tid < 128) p_lds[tid] = expf(s_lds[tid] - vm);
    __syncthreads();
    float vs = p_lds[lane] + p_lds[64 + lane];
#pragma unroll
    for (int mo = 32; mo > 0; mo >>= 1) vs += __shfl_xor(vs, mo, 64);
    float rsum = 1.0f / vs;
    if (tid < 96) {
      int jg = (tid >> 5) * 512 + i0 + (tid & 31);
      float acc = 0.f;
#pragma unroll 8
      for (int t = 0; t < 128; ++t) acc += p_lds[t] * bf2f(P_lds[t][tid]);
      gi_l[tid] = ws_gix[(size_t)((s << 4) + bP) * 1536 + jg] + acc * rsum;
      gh_l[tid] = ld_sys(&ws_gh[bP * 1536 + jg]);
    }
    __syncthreads();
    if (tid < 32) {
      int i = i0 + tid;
      float rg = 1.f / (1.f + expf(-(gi_l[tid] + gh_l[tid])));
      float zg = 1.f / (1.f + expf(-(gi_l[32 + tid] + gh_l[32 + tid])));
      float ng = tanhf(gi_l[64 + tid] + rg * gh_l[64 + tid]);
      float hold = ld_sys(&hbase[(bP << 9) + i]);
      float hn = (1.f - zg) * ng + zg * hold;
      st_sys(&ws_hall[(size_t)((s << 4) + bP) * 512 + i], hn);
    }
    gbar(bars, ++phase);
  }

  // hT output
  if (k < 16) {
    for (int i = tid; i < 512; i += 256)
      outT[(k << 9) + i] = ld_sys(&ws_hall[(size_t)(126 * 16 + k) * 512 + i]);
  }
}

// ---------------- launch ----------------
extern "C" void kernel_launch(void* const* d_in, const int* in_sizes, int n_in,
                              void* d_out, int out_size, void* d_ws, size_t ws_size,
                              hipStream_t stream) {
  const float* enc  = (const float*)d_in[0];
  const float* ehid = (const float*)d_in[1];
  const int*   mask = (const int*)d_in[2];
  const int*   tgt  = (const int*)d_in[3];
  const float* emb  = (const float*)d_in[4];
  const float* Wq   = (const float*)d_in[5];
  const float* bq   = (const float*)d_in[6];
  const float* Wv   = (const float*)d_in[7];
  const float* bv   = (const float*)d_in[8];
  const float* Wc   = (const float*)d_in[9];
  const float* bc   = (const float*)d_in[10];
  const float* Wih  = (const float*)d_in[11];
  const float* Whh  = (const float*)d_in[12];
  const float* bih  = (const float*)d_in[13];
  const float* bhh  = (const float*)d_in[14];
  const float* Wo   = (const float*)d_in[15];
  const float* bo   = (const float*)d_in[16];

  float* out = (float*)d_out;
  float* ws  = (float*)d_ws;
  float* vt   = ws + OFF_VT;
  float* P    = ws + OFF_P;
  float* gix  = ws + OFF_GIX;
  float* hall = ws + OFF_HALL;
  float* q    = ws + OFF_Q;
  float* gh   = ws + OFF_GH;
  float* sc   = ws + OFF_SC;
  u32*   bars = (u32*)(ws + OFF_BAR);
  u16* A_enc = (u16*)(ws + OFF_AENC);
  u16* A_emb = (u16*)(ws + OFF_AEMB);
  u16* A_h   = (u16*)(ws + OFF_AH);
  u16* B_wv  = (u16*)(ws + OFF_BWV);
  u16* B_wi1 = (u16*)(ws + OFF_BWIH1);
  u16* B_wi2 = (u16*)(ws + OFF_BWIH2);
  u16* B_wo  = (u16*)(ws + OFF_BWO);

  k_init<<<2000, 256, 0, stream>>>(out, bars);
  k_f2bf<<<4096, 256, 0, stream>>>(enc, A_enc, 1048576);
  k_f2bf<<<1024, 256, 0, stream>>>(Wv, B_wv, 262144);
  k_f2bf_sub<<<3072, 256, 0, stream>>>(Wih, B_wi1, 786432, 1024, 0);
  k_f2bf_sub<<<3072, 256, 0, stream>>>(Wih, B_wi2, 786432, 1024, 512);
  k_f2bf<<<64000, 256, 0, stream>>>(Wo, B_wo, 16384000);
  k_gather<<<4064, 256, 0, stream>>>(emb, tgt, A_emb, 1040384);

  // vt = enc @ Wv.T + bv            [2048 x 512]
  gemm_bf16<<<dim3(4, 16), 256, 0, stream>>>(A_enc, B_wv, bv, vt, 512, 0);
  // P  = enc @ Wih[:,H:].T          [2048 x 1536]
  gemm_bf16<<<dim3(12, 16), 256, 0, stream>>>(A_enc, B_wi2, nullptr, P, 1536, 0);
  // gi_x = emb[toks] @ Wih[:,:H].T + bih   [2032 x 1536]
  gemm_bf16<<<dim3(12, 16), 256, 0, stream>>>(A_emb, B_wi1, bih, gix, 1536, 0);

  seq_kernel<<<256, 256, 0, stream>>>(Wq, bq, Wc, bc, Whh, bhh,
                                      ehid, mask, vt, P, gix, hall, q, gh, sc, bars,
                                      out + 65536000);

  k_f2bf<<<4064, 256, 0, stream>>>(hall, A_h, 1040384);
  // logits = h_all @ Wo.T + bo -> out[:,1:,:]
  gemm_bf16<<<dim3(250, 16), 256, 0, stream>>>(A_h, B_wo, bo, out, 32000, 1);
}